// Round 1
// baseline (14880.161 us; speedup 1.0000x reference)
//
#include <hip/hip_runtime.h>
#include <math.h>

#define B_ 64
#define S_ 512
#define I_ 300
#define H_ 512
#define G_ 2048   // 4*H
#define T_ 25
#define K_ 812    // I_ + H_

// ---------------- workspace layout (float elements) ----------------
static constexpr size_t SZ_XT   = (size_t)S_ * I_ * B_;        // 9,830,400
static constexpr size_t OFS_XT  = 0;
static constexpr size_t OFS_XRT = OFS_XT + SZ_XT;
static constexpr size_t SZ_WC   = (size_t)2 * G_ * K_;         // 3,325,952
static constexpr size_t OFS_WC  = OFS_XRT + SZ_XT;
static constexpr size_t OFS_H0  = OFS_WC + SZ_WC;
static constexpr size_t OFS_H1  = OFS_H0 + (size_t)2 * H_ * B_;
static constexpr size_t OFS_C   = OFS_H1 + (size_t)2 * H_ * B_;
static constexpr size_t OFS_YF  = OFS_C + (size_t)2 * H_ * B_;
static constexpr size_t SZ_Y    = (size_t)S_ * H_ * B_;        // 16,777,216
static constexpr size_t OFS_YB  = OFS_YF + SZ_Y;
static constexpr size_t SZ_L    = (size_t)B_ * S_ * T_;        // 819,200
static constexpr size_t OFS_L1  = OFS_YB + SZ_Y;
static constexpr size_t OFS_L2  = OFS_L1 + SZ_L;
static constexpr size_t OFS_LEN = OFS_L2 + SZ_L;   // int32[64]
static constexpr size_t OFS_LLH = OFS_LEN + 64;    // float[64]
// total ~58.4M floats = ~234 MB of workspace

// output layout (float elements in d_out)
static constexpr size_t OFF_LOGITS = 1;
static constexpr size_t OFF_TAGS   = 1 + SZ_L;           // 819,201
static constexpr size_t OFF_MASK   = OFF_TAGS + (size_t)B_ * S_; // 851,969

// ---------------- small utility kernels ----------------
__global__ void k_lengths(const int* __restrict__ am, int* __restrict__ len) {
    int b = threadIdx.x;
    int sum = 0;
    for (int s = 0; s < S_; ++s) sum += am[b * S_ + s];
    len[b] = sum;
}

__global__ void k_zero(float* __restrict__ p, int n) {
    int idx = blockIdx.x * 256 + threadIdx.x;
    if (idx < n) p[idx] = 0.f;
}

// Build combined weights Wcomb[dir][row(2048)][k(812)] = [W_ih row | W_hh row]
__global__ void k_prep_w(const float* __restrict__ wihf, const float* __restrict__ whhf,
                         const float* __restrict__ wihb, const float* __restrict__ whhb,
                         float* __restrict__ wcomb) {
    size_t total = (size_t)2 * G_ * K_;
    for (size_t idx = (size_t)blockIdx.x * 256 + threadIdx.x; idx < total;
         idx += (size_t)gridDim.x * 256) {
        int dir = (int)(idx / ((size_t)G_ * K_));
        int r   = (int)(idx % ((size_t)G_ * K_));
        int row = r / K_;
        int k   = r % K_;
        const float* wih = dir ? wihb : wihf;
        const float* whh = dir ? whhb : whhf;
        wcomb[idx] = (k < I_) ? wih[(size_t)row * I_ + k]
                              : whh[(size_t)row * H_ + (k - I_)];
    }
}

// Transpose x[b][s][i] -> x_t[s][i][b]; rev variant gathers per-batch reversed rows.
__global__ __launch_bounds__(256) void k_transpose(const float* __restrict__ x,
                                                   const int* __restrict__ len,
                                                   float* __restrict__ xt,
                                                   float* __restrict__ xrt) {
    __shared__ float tile[B_][153];  // pad 153: gcd(153%32=25,32)=1 -> conflict-free
    int bid = blockIdx.x;
    int s = bid & 511;
    int isrev = bid >> 9;   // grid = 1024
    int tid = threadIdx.x;
    float* dst = (isrev ? xrt : xt) + (size_t)s * I_ * B_;
    for (int c = 0; c < 2; ++c) {
        int i0 = c * 150;
        for (int b2 = 0; b2 < B_; ++b2) {
            int src = s;
            if (isrev) { int L = len[b2]; src = (s < L) ? (L - 1 - s) : s; }
            for (int i = tid; i < 150; i += 256)
                tile[b2][i] = x[((size_t)b2 * S_ + src) * I_ + i0 + i];
        }
        __syncthreads();
        for (int idx = tid; idx < 150 * B_; idx += 256) {
            int i = idx >> 6;
            int b2 = idx & 63;
            dst[(size_t)(i0 + i) * B_ + b2] = tile[b2][i];
        }
        __syncthreads();
    }
}

// One LSTM time step, both directions. 256 blocks: dir = bid>>7, 4 hidden units/block.
// wave w (tid>>6) owns unit u = (bid&127)*4 + w; lane = batch b.
__global__ __launch_bounds__(256) void k_lstm_step(
    int s,
    const float* __restrict__ wcomb,
    const float* __restrict__ xt, const float* __restrict__ xrt,
    const float* __restrict__ h_in, float* __restrict__ h_out,
    float* __restrict__ c_st,
    float* __restrict__ yf, float* __restrict__ ybr,
    const float* __restrict__ bf, const float* __restrict__ bb,
    const int* __restrict__ len) {
    __shared__ float wlds[4][4][K_];   // 51,968 B
    int dir = blockIdx.x >> 7;
    int ug  = blockIdx.x & 127;
    int w   = threadIdx.x >> 6;
    int b   = threadIdx.x & 63;
    int u   = ug * 4 + w;

    // wave w loads its unit's 4 gate rows
    for (int g = 0; g < 4; ++g) {
        const float* src = wcomb + ((size_t)dir * G_ + g * H_ + u) * K_;
        for (int k = b; k < K_; k += 64) wlds[w][g][k] = src[k];
    }
    __syncthreads();

    const float* bias = dir ? bb : bf;
    float ai = bias[0 * H_ + u];
    float af = bias[1 * H_ + u];
    float ag = bias[2 * H_ + u];
    float ao = bias[3 * H_ + u];

    const float4* wv0 = (const float4*)&wlds[w][0][0];
    const float4* wv1 = (const float4*)&wlds[w][1][0];
    const float4* wv2 = (const float4*)&wlds[w][2][0];
    const float4* wv3 = (const float4*)&wlds[w][3][0];

    const float* xrow = (dir ? xrt : xt) + (size_t)s * I_ * B_ + b;
    for (int k4 = 0; k4 < I_ / 4; ++k4) {
        float a0 = xrow[(size_t)(k4 * 4 + 0) * B_];
        float a1 = xrow[(size_t)(k4 * 4 + 1) * B_];
        float a2 = xrow[(size_t)(k4 * 4 + 2) * B_];
        float a3 = xrow[(size_t)(k4 * 4 + 3) * B_];
        float4 w0v = wv0[k4], w1v = wv1[k4], w2v = wv2[k4], w3v = wv3[k4];
        ai += a0 * w0v.x + a1 * w0v.y + a2 * w0v.z + a3 * w0v.w;
        af += a0 * w1v.x + a1 * w1v.y + a2 * w1v.z + a3 * w1v.w;
        ag += a0 * w2v.x + a1 * w2v.y + a2 * w2v.z + a3 * w2v.w;
        ao += a0 * w3v.x + a1 * w3v.y + a2 * w3v.z + a3 * w3v.w;
    }
    const float* hrow = h_in + (size_t)dir * H_ * B_ + b;
    const int base4 = I_ / 4;  // 75
    for (int k4 = 0; k4 < H_ / 4; ++k4) {
        float a0 = hrow[(size_t)(k4 * 4 + 0) * B_];
        float a1 = hrow[(size_t)(k4 * 4 + 1) * B_];
        float a2 = hrow[(size_t)(k4 * 4 + 2) * B_];
        float a3 = hrow[(size_t)(k4 * 4 + 3) * B_];
        float4 w0v = wv0[base4 + k4], w1v = wv1[base4 + k4],
               w2v = wv2[base4 + k4], w3v = wv3[base4 + k4];
        ai += a0 * w0v.x + a1 * w0v.y + a2 * w0v.z + a3 * w0v.w;
        af += a0 * w1v.x + a1 * w1v.y + a2 * w1v.z + a3 * w1v.w;
        ag += a0 * w2v.x + a1 * w2v.y + a2 * w2v.z + a3 * w2v.w;
        ao += a0 * w3v.x + a1 * w3v.y + a2 * w3v.z + a3 * w3v.w;
    }

    int L = len[b];
    bool valid = (s < L);
    size_t sidx = ((size_t)dir * H_ + u) * B_ + b;
    float hp = hrow[(size_t)u * B_];
    float cp = c_st[sidx];
    float ii = 1.f / (1.f + expf(-ai));
    float ff = 1.f / (1.f + expf(-af));
    float gg = tanhf(ag);
    float oo = 1.f / (1.f + expf(-ao));
    float cn = ff * cp + ii * gg;
    float hn = oo * tanhf(cn);
    h_out[sidx] = valid ? hn : hp;
    if (valid) c_st[sidx] = cn;
    float* y = (dir ? ybr : yf) + ((size_t)s * H_ + u) * B_ + b;
    *y = valid ? hn : 0.f;
}

// logits halves: part0: L1[b][s][t] = sum_h yf[s][h][b]*Wc[t][h] + bc[t]
//                part1: L2[b][s'][t] = sum_h ybr[s'][h][b]*Wc[t][512+h]
__global__ __launch_bounds__(256) void k_logits(const float* __restrict__ yf,
                                                const float* __restrict__ ybr,
                                                const float* __restrict__ wc,
                                                const float* __restrict__ bcv,
                                                float* __restrict__ L1,
                                                float* __restrict__ L2p) {
    __shared__ float smem[T_ * H_];  // 51,200 B (reused as partial buffer later)
    int part = blockIdx.x >> 9;
    int s = blockIdx.x & 511;
    int tid = threadIdx.x;
    const float* y = part ? ybr : yf;
    float* Ldst = part ? L2p : L1;
    for (int idx = tid; idx < T_ * H_; idx += 256) {
        int t = idx >> 9;
        int h = idx & 511;
        smem[idx] = wc[(size_t)t * 1024 + part * 512 + h];
    }
    __syncthreads();
    int q = tid >> 6, b = tid & 63;
    float acc[T_];
#pragma unroll
    for (int t = 0; t < T_; ++t) acc[t] = 0.f;
    const float* yrow = y + (size_t)s * H_ * B_ + b;
    for (int h = q * 128; h < q * 128 + 128; ++h) {
        float a = yrow[(size_t)h * B_];
#pragma unroll
        for (int t = 0; t < T_; ++t) acc[t] += a * smem[t * H_ + h];
    }
    __syncthreads();  // done reading weights; reuse smem for partials
    float* pl = smem; // pl[(q*64+b)*26 + t], 6656 floats
#pragma unroll
    for (int t = 0; t < T_; ++t) pl[(q * 64 + b) * 26 + t] = acc[t];
    __syncthreads();
    for (int idx = tid; idx < B_ * T_; idx += 256) {
        int bb2 = idx / T_;
        int t = idx - bb2 * T_;
        float v = pl[(0 * 64 + bb2) * 26 + t] + pl[(1 * 64 + bb2) * 26 + t] +
                  pl[(2 * 64 + bb2) * 26 + t] + pl[(3 * 64 + bb2) * 26 + t];
        if (!part) v += bcv[t];
        Ldst[((size_t)bb2 * S_ + s) * T_ + t] = v;
    }
}

// logits[b][s][t] = L1[b][s][t] + L2[b][rev(b,s)][t]
__global__ void k_combine(const float* __restrict__ L1, const float* __restrict__ L2p,
                          const int* __restrict__ len, float* __restrict__ outlog) {
    int id = blockIdx.x * 256 + threadIdx.x;  // 32768 = B*S
    int b = id >> 9;
    int s = id & 511;
    int L = len[b];
    int sr = (s < L) ? (L - 1 - s) : s;
    const float* p1 = L1 + ((size_t)b * S_ + s) * T_;
    const float* p2 = L2p + ((size_t)b * S_ + sr) * T_;
    float* o = outlog + ((size_t)b * S_ + s) * T_;
#pragma unroll
    for (int t = 0; t < T_; ++t) o[t] = p1[t] + p2[t];
}

// CRF NLL per batch element: forward logsumexp + numerator; llh[b] = num - denom
__global__ __launch_bounds__(64) void k_crf_nll(const float* __restrict__ em,
                                                const int* __restrict__ labels,
                                                const int* __restrict__ len,
                                                const float* __restrict__ cs,
                                                const float* __restrict__ ce,
                                                const float* __restrict__ ctr,
                                                float* __restrict__ llh) {
    int b = blockIdx.x, tid = threadIdx.x;
    __shared__ float tr[T_ * T_];
    __shared__ float sa[T_], sb[T_];
    for (int idx = tid; idx < T_ * T_; idx += 64) tr[idx] = ctr[idx];
    const float* e = em + (size_t)b * S_ * T_;
    int L = len[b];
    if (tid < T_) sa[tid] = cs[tid] + e[tid];
    __syncthreads();
    float* cur = sa;
    float* nx = sb;
    for (int t = 1; t < L; ++t) {
        if (tid < T_) {
            float m = -1e30f;
            for (int i = 0; i < T_; ++i) m = fmaxf(m, cur[i] + tr[i * T_ + tid]);
            float ssum = 0.f;
            for (int i = 0; i < T_; ++i) ssum += expf(cur[i] + tr[i * T_ + tid] - m);
            nx[tid] = m + logf(ssum) + e[(size_t)t * T_ + tid];
        }
        __syncthreads();
        float* tmp = cur; cur = nx; nx = tmp;
    }
    // numerator partial over lanes
    float part = 0.f;
    for (int t = tid; t < S_; t += 64) {
        if (t >= 1 && t < L) {
            int lp = labels[b * S_ + t - 1];
            int lc = labels[b * S_ + t];
            part += tr[lp * T_ + lc] + e[(size_t)t * T_ + lc];
        }
    }
    for (int off = 32; off; off >>= 1) part += __shfl_down(part, off, 64);
    if (tid == 0) {
        float m = -1e30f;
        for (int j = 0; j < T_; ++j) m = fmaxf(m, cur[j] + ce[j]);
        float ssum = 0.f;
        for (int j = 0; j < T_; ++j) ssum += expf(cur[j] + ce[j] - m);
        float denom = m + logf(ssum);
        int l0 = labels[b * S_];
        int lL = labels[b * S_ + L - 1];
        float num = cs[l0] + e[l0] + part + ce[lL];
        llh[b] = num - denom;
    }
}

__global__ void k_loss(const float* __restrict__ llh, const int* __restrict__ len,
                       float* __restrict__ out0) {
    int tid = threadIdx.x;
    float v = llh[tid];
    float n = (float)len[tid];
    for (int off = 32; off; off >>= 1) {
        v += __shfl_down(v, off, 64);
        n += __shfl_down(n, off, 64);
    }
    if (tid == 0) out0[0] = -(v / n);
}

// Viterbi decode per batch element; writes tags (as float) and pred_mask (as float)
__global__ __launch_bounds__(64) void k_viterbi(const float* __restrict__ em,
                                                const int* __restrict__ len,
                                                const float* __restrict__ cs,
                                                const float* __restrict__ ce,
                                                const float* __restrict__ ctr,
                                                float* __restrict__ otags,
                                                float* __restrict__ omask) {
    int b = blockIdx.x, tid = threadIdx.x;
    __shared__ float tr[T_ * T_];
    __shared__ float sa[T_], sb[T_];
    __shared__ unsigned char hist[(S_ - 1) * T_];  // 12,775 B
    __shared__ unsigned char tg[S_];
    for (int idx = tid; idx < T_ * T_; idx += 64) tr[idx] = ctr[idx];
    const float* e = em + (size_t)b * S_ * T_;
    int L = len[b];
    if (tid < T_) sa[tid] = cs[tid] + e[tid];
    __syncthreads();
    float* cur = sa;
    float* nx = sb;
    for (int t = 1; t < L; ++t) {
        if (tid < T_) {
            float best = -1e30f;
            int bi = 0;
            for (int i = 0; i < T_; ++i) {
                float v = cur[i] + tr[i * T_ + tid];
                if (v > best) { best = v; bi = i; }  // strict > keeps first max
            }
            nx[tid] = best + e[(size_t)t * T_ + tid];
            hist[(t - 1) * T_ + tid] = (unsigned char)bi;
        }
        __syncthreads();
        float* tmp = cur; cur = nx; nx = tmp;
    }
    if (tid == 0) {
        float best = -1e30f;
        int bt = 0;
        for (int j = 0; j < T_; ++j) {
            float v = cur[j] + ce[j];
            if (v > best) { best = v; bt = j; }
        }
        tg[S_ - 1] = (unsigned char)bt;
        for (int t = S_ - 2; t >= 0; --t) {
            if (t + 1 < L) bt = hist[t * T_ + bt];  // mask[t+1] == (t+1 < L)
            tg[t] = (unsigned char)bt;
        }
    }
    __syncthreads();
    for (int idx = tid; idx < S_; idx += 64) {
        otags[(size_t)b * S_ + idx] = (float)tg[idx];
        omask[(size_t)b * S_ + idx] = (idx < L) ? 1.f : 0.f;
    }
}

// ---------------- host launch ----------------
extern "C" void kernel_launch(void* const* d_in, const int* in_sizes, int n_in,
                              void* d_out, int out_size, void* d_ws, size_t ws_size,
                              hipStream_t stream) {
    const float* x    = (const float*)d_in[0];
    const float* wihf = (const float*)d_in[1];
    const float* whhf = (const float*)d_in[2];
    const float* bf   = (const float*)d_in[3];
    const float* wihb = (const float*)d_in[4];
    const float* whhb = (const float*)d_in[5];
    const float* bb   = (const float*)d_in[6];
    const float* wc   = (const float*)d_in[7];
    const float* bc   = (const float*)d_in[8];
    const float* cs   = (const float*)d_in[9];
    const float* ce   = (const float*)d_in[10];
    const float* ctr  = (const float*)d_in[11];
    const int* am     = (const int*)d_in[12];
    const int* labels = (const int*)d_in[13];

    float* ws   = (float*)d_ws;
    float* xt   = ws + OFS_XT;
    float* xrt  = ws + OFS_XRT;
    float* wcmb = ws + OFS_WC;
    float* h0   = ws + OFS_H0;
    float* h1   = ws + OFS_H1;
    float* cst  = ws + OFS_C;
    float* yf   = ws + OFS_YF;
    float* ybr  = ws + OFS_YB;
    float* L1p  = ws + OFS_L1;
    float* L2p  = ws + OFS_L2;
    int*   lenp = (int*)(ws + OFS_LEN);
    float* llhp = ws + OFS_LLH;
    float* out  = (float*)d_out;

    k_lengths<<<1, 64, 0, stream>>>(am, lenp);
    k_prep_w<<<2048, 256, 0, stream>>>(wihf, whhf, wihb, whhb, wcmb);
    k_zero<<<768, 256, 0, stream>>>(h0, 3 * 2 * H_ * B_);  // h0,h1,c contiguous
    k_transpose<<<1024, 256, 0, stream>>>(x, lenp, xt, xrt);

    for (int s = 0; s < S_; ++s) {
        const float* hin = (s & 1) ? h1 : h0;
        float* hout      = (s & 1) ? h0 : h1;
        k_lstm_step<<<256, 256, 0, stream>>>(s, wcmb, xt, xrt, hin, hout, cst,
                                             yf, ybr, bf, bb, lenp);
    }

    k_logits<<<1024, 256, 0, stream>>>(yf, ybr, wc, bc, L1p, L2p);
    k_combine<<<128, 256, 0, stream>>>(L1p, L2p, lenp, out + OFF_LOGITS);
    k_crf_nll<<<64, 64, 0, stream>>>(out + OFF_LOGITS, labels, lenp, cs, ce, ctr, llhp);
    k_loss<<<1, 64, 0, stream>>>(llhp, lenp, out);
    k_viterbi<<<64, 64, 0, stream>>>(out + OFF_LOGITS, lenp, cs, ce, ctr,
                                     out + OFF_TAGS, out + OFF_MASK);
}